// Round 2
// baseline (207.148 us; speedup 1.0000x reference)
//
#include <hip/hip_runtime.h>
#include <math.h>

// DynamicRelationModeler: x=concat(img,txt) [512x512]; per r: a=x@Wl_r^T, b=x@Wr_r^T;
// h=a_i+b_j+b1_r; LN over H; s=relu(hn)@w2_r+b2_r; argmax/max over r; mask.
//
// Score decomposition (exact): relu(z) = (z+|z|)/2, so with P=0.5*w2*gamma, Q=0.5*w2*beta:
//   s = sv*(PA'_i + PB'_j) + QS_r + sum_k sign(w2_k)*|t_k*P_k + Q_k| + b2_r
// where t_k = (a_ik + b_jk - mu)*sv, PA'_i = sum_k P_k*(a_ik - ma_i)  (per-row precompute).
// Inner loop = 4 VALU ops per (pair,k): add, fma, fma, fma-with-abs-modifier.
//
// ws layout (floats):
//   Aarr [4][512][512], Barr [4][512][512] (b1 folded), dotp [2][4][512][512],
//   Spart[2][4][512][512], then small arrays (row stats, planes) at 24*PLANE.

namespace {
constexpr size_t PLANE  = 512 * 512;            // 262144
constexpr size_t OFF_A   = 0;
constexpr size_t OFF_B   = OFF_A + 4 * PLANE;
constexpr size_t OFF_DOT = OFF_B + 4 * PLANE;
constexpr size_t OFF_S   = OFF_DOT + 8 * PLANE;
constexpr size_t OFF_MA  = OFF_S + 8 * PLANE;   // 24*PLANE
constexpr size_t OFF_QA  = OFF_MA + 2048;
constexpr size_t OFF_PAp = OFF_QA + 2048;
constexpr size_t OFF_MB  = OFF_PAp + 2048;
constexpr size_t OFF_QB  = OFF_MB + 2048;
constexpr size_t OFF_PBp = OFF_QB + 2048;
constexpr size_t OFF_P   = OFF_PBp + 2048;
constexpr size_t OFF_Q   = OFF_P + 2048;
constexpr size_t OFF_SG  = OFF_Q + 2048;
constexpr size_t OFF_QSP = OFF_SG + 2048;       // 8 floats
}

// ---------------- K0: input GEMM  C[n][4096] = x @ [Wl|Wr]^T ----------------
__global__ __launch_bounds__(256) void k0_gemm(const float* __restrict__ img,
                                               const float* __restrict__ txt,
                                               const float* __restrict__ W1,
                                               const float* __restrict__ b1,
                                               float* __restrict__ ws) {
  const int b = blockIdx.x;
  const int it = b >> 6;
  const int ct = b & 63;
  const int which = ct >> 5;
  const int r = (ct >> 3) & 3;
  const int ht = ct & 7;
  const int i0 = it << 6, h0 = ht << 6;
  const int t = threadIdx.x;
  const int tx = t & 15, ty = t >> 4;

  __shared__ float Xs[16 * 68];
  __shared__ float Wsm[16 * 68];

  float acc[16], pacc[16];
#pragma unroll
  for (int p = 0; p < 16; ++p) { acc[p] = 0.f; pacc[p] = 0.f; }

  const int srow = t >> 2;
  const int sf4 = (t & 3) << 2;
  const int xi = i0 + srow;
  const float* xrow = (xi < 256) ? (img + (size_t)xi * 512)
                                 : (txt + (size_t)(xi - 256) * 512);
  const float* wrow = W1 + (size_t)(r * 512 + h0 + srow) * 1024 + which * 512;

  for (int k0 = 0; k0 < 512; k0 += 16) {
    const float4 xv = *(const float4*)(xrow + k0 + sf4);
    const float4 wv = *(const float4*)(wrow + k0 + sf4);
    __syncthreads();
    Xs[(sf4 + 0) * 68 + srow] = xv.x;
    Xs[(sf4 + 1) * 68 + srow] = xv.y;
    Xs[(sf4 + 2) * 68 + srow] = xv.z;
    Xs[(sf4 + 3) * 68 + srow] = xv.w;
    Wsm[(sf4 + 0) * 68 + srow] = wv.x;
    Wsm[(sf4 + 1) * 68 + srow] = wv.y;
    Wsm[(sf4 + 2) * 68 + srow] = wv.z;
    Wsm[(sf4 + 3) * 68 + srow] = wv.w;
    __syncthreads();
#pragma unroll
    for (int k = 0; k < 16; ++k) {
      const float4 a4 = *(const float4*)&Xs[k * 68 + 4 * ty];
      const float4 b4 = *(const float4*)&Wsm[k * 68 + 4 * tx];
      const float av[4] = {a4.x, a4.y, a4.z, a4.w};
      const float bv[4] = {b4.x, b4.y, b4.z, b4.w};
#pragma unroll
      for (int c = 0; c < 4; ++c)
#pragma unroll
        for (int d = 0; d < 4; ++d)
          pacc[c * 4 + d] = fmaf(av[c], bv[d], pacc[c * 4 + d]);
    }
#pragma unroll
    for (int p = 0; p < 16; ++p) { acc[p] += pacc[p]; pacc[p] = 0.f; }
  }

  float4 bb = make_float4(0.f, 0.f, 0.f, 0.f);
  if (which) bb = *(const float4*)(b1 + r * 512 + h0 + 4 * tx);
  float* dst = ws + (which ? OFF_B : OFF_A) + (size_t)r * PLANE;
#pragma unroll
  for (int c = 0; c < 4; ++c) {
    float4 v;
    v.x = acc[c * 4 + 0] + bb.x;
    v.y = acc[c * 4 + 1] + bb.y;
    v.z = acc[c * 4 + 2] + bb.z;
    v.w = acc[c * 4 + 3] + bb.w;
    *(float4*)(dst + (size_t)(i0 + 4 * ty + c) * 512 + h0 + 4 * tx) = v;
  }
}

// ---------------- K1: row stats + weighted row sums + planes ----------------
// one wave per (which, r, row); grid 1024 x 256; blocks <8 also pack planes.
__global__ __launch_bounds__(256) void k1_stats(float* __restrict__ ws,
                                                const float* __restrict__ gamma,
                                                const float* __restrict__ beta,
                                                const float* __restrict__ w2) {
  __shared__ float red[4];
  const int t = threadIdx.x;
  const int gw = (blockIdx.x * 256 + t) >> 6;
  const int lane = t & 63;
  const int which = gw >> 11;
  const int rr = (gw >> 9) & 3;
  const int row = gw & 511;
  const float* src =
      ws + (which ? OFF_B : OFF_A) + (size_t)(rr * 512 + row) * 512 + lane * 8;
  const float* gp = gamma + rr * 512 + lane * 8;
  const float* wp = w2 + rr * 512 + lane * 8;
  float s = 0.f, q = 0.f, pa = 0.f, gg = 0.f;
#pragma unroll
  for (int c = 0; c < 2; ++c) {
    const float4 v = *(const float4*)(src + c * 4);
    const float4 g = *(const float4*)(gp + c * 4);
    const float4 w = *(const float4*)(wp + c * 4);
    const float vv[4] = {v.x, v.y, v.z, v.w};
    const float gv[4] = {g.x, g.y, g.z, g.w};
    const float wv[4] = {w.x, w.y, w.z, w.w};
#pragma unroll
    for (int e = 0; e < 4; ++e) {
      const float p = 0.5f * gv[e] * wv[e];
      s += vv[e];
      q += vv[e] * vv[e];
      pa += p * vv[e];
      gg += p;
    }
  }
#pragma unroll
  for (int off = 32; off >= 1; off >>= 1) {
    s += __shfl_down(s, off, 64);
    q += __shfl_down(q, off, 64);
    pa += __shfl_down(pa, off, 64);
    gg += __shfl_down(gg, off, 64);
  }
  if (lane == 0) {
    const float ma = s * (1.f / 512.f);
    ws[(which ? OFF_MB : OFF_MA) + rr * 512 + row] = ma;
    ws[(which ? OFF_QB : OFF_QA) + rr * 512 + row] = q;
    ws[(which ? OFF_PBp : OFF_PAp) + rr * 512 + row] = pa - ma * gg;
  }
  if (blockIdx.x < 8) {
    const int idx = blockIdx.x * 256 + t;  // r*512+k
    const float g = gamma[idx], be = beta[idx], w = w2[idx];
    const float qv = 0.5f * be * w;
    ws[OFF_P + idx] = 0.5f * g * w;
    ws[OFF_Q + idx] = qv;
    ws[OFF_SG + idx] = copysignf(1.f, w);
    float qs = qv;
#pragma unroll
    for (int off = 32; off >= 1; off >>= 1) qs += __shfl_down(qs, off, 64);
    if (lane == 0) red[t >> 6] = qs;
    __syncthreads();
    if (t == 0) ws[OFF_QSP + blockIdx.x] = red[0] + red[1] + red[2] + red[3];
  }
}

// ---------------- K2: pairwise dot  dotp[ks][r][i][j] = sum_k a.b' ----------------
__global__ __launch_bounds__(256) void k2_dot(float* __restrict__ ws) {
  const int b = blockIdx.x;
  const int jt = b & 7, it = (b >> 3) & 7, r = (b >> 6) & 3, ks = b >> 8;
  const int i0 = it << 6, j0 = jt << 6;
  const int kb = ks << 8;
  const int t = threadIdx.x;
  const int tx = t & 15, ty = t >> 4;

  __shared__ float As[16 * 68];
  __shared__ float Bs[16 * 68];

  float acc[16];
#pragma unroll
  for (int p = 0; p < 16; ++p) acc[p] = 0.f;

  const int srow = t >> 2, sf4 = (t & 3) << 2;
  const float* arow = ws + OFF_A + (size_t)(r * 512 + i0 + srow) * 512 + kb;
  const float* brow = ws + OFF_B + (size_t)(r * 512 + j0 + srow) * 512 + kb;

  for (int k0 = 0; k0 < 256; k0 += 16) {
    const float4 av = *(const float4*)(arow + k0 + sf4);
    const float4 bv = *(const float4*)(brow + k0 + sf4);
    __syncthreads();
    As[(sf4 + 0) * 68 + srow] = av.x;
    As[(sf4 + 1) * 68 + srow] = av.y;
    As[(sf4 + 2) * 68 + srow] = av.z;
    As[(sf4 + 3) * 68 + srow] = av.w;
    Bs[(sf4 + 0) * 68 + srow] = bv.x;
    Bs[(sf4 + 1) * 68 + srow] = bv.y;
    Bs[(sf4 + 2) * 68 + srow] = bv.z;
    Bs[(sf4 + 3) * 68 + srow] = bv.w;
    __syncthreads();
#pragma unroll
    for (int k = 0; k < 16; ++k) {
      const float4 a4 = *(const float4*)&As[k * 68 + 4 * ty];
      const float4 b4 = *(const float4*)&Bs[k * 68 + 4 * tx];
      const float av2[4] = {a4.x, a4.y, a4.z, a4.w};
      const float bv2[4] = {b4.x, b4.y, b4.z, b4.w};
#pragma unroll
      for (int c = 0; c < 4; ++c)
#pragma unroll
        for (int d = 0; d < 4; ++d)
          acc[c * 4 + d] = fmaf(av2[c], bv2[d], acc[c * 4 + d]);
    }
  }
  float* dst = ws + OFF_DOT + (size_t)ks * (4 * PLANE) + (size_t)r * PLANE;
#pragma unroll
  for (int c = 0; c < 4; ++c) {
    float4 v;
    v.x = acc[c * 4 + 0]; v.y = acc[c * 4 + 1];
    v.z = acc[c * 4 + 2]; v.w = acc[c * 4 + 3];
    *(float4*)(dst + (size_t)(i0 + 4 * ty + c) * 512 + j0 + 4 * tx) = v;
  }
}

// ---------------- K3: score kernel (4-op inner loop) ----------------
// grid 512 = 8jt x 8it x 4r x 2ks; block 256 (16tx x 16ty; 4i x 4j reg tile)
// LDS: [row][k] 64x64 per array, 16B chunks XOR-swizzled: chunk = k4 ^ ((row+(row>>2))&15)
__global__ __launch_bounds__(256) void k3_score(float* __restrict__ ws) {
  const int b = blockIdx.x;
  const int jt = b & 7, it = (b >> 3) & 7, r = (b >> 6) & 3, ks = b >> 8;
  const int i0 = it << 6, j0 = jt << 6;
  const int t = threadIdx.x;
  const int tx = t & 15, ty = t >> 4;

  __shared__ float As[64 * 64];
  __shared__ float Bs[64 * 64];
  __shared__ float Pl[3 * 64];  // P | Q | sign planes for current 64-k chunk

  const float4 mav = *(const float4*)(ws + OFF_MA + r * 512 + i0 + 4 * ty);
  const float4 qav = *(const float4*)(ws + OFF_QA + r * 512 + i0 + 4 * ty);
  const float4 pav = *(const float4*)(ws + OFF_PAp + r * 512 + i0 + 4 * ty);
  const float4 mbv = *(const float4*)(ws + OFF_MB + r * 512 + j0 + 4 * tx);
  const float4 qbv = *(const float4*)(ws + OFF_QB + r * 512 + j0 + 4 * tx);
  const float4 pbv = *(const float4*)(ws + OFF_PBp + r * 512 + j0 + 4 * tx);
  const float maA[4] = {mav.x, mav.y, mav.z, mav.w};
  const float qaA[4] = {qav.x, qav.y, qav.z, qav.w};
  const float paA[4] = {pav.x, pav.y, pav.z, pav.w};
  const float mbA[4] = {mbv.x, mbv.y, mbv.z, mbv.w};
  const float qbA[4] = {qbv.x, qbv.y, qbv.z, qbv.w};
  const float pbA[4] = {pbv.x, pbv.y, pbv.z, pbv.w};

  float Sv[16], Tv[16], acc[16];
#pragma unroll
  for (int c = 0; c < 4; ++c) {
    const size_t doff =
        (size_t)r * PLANE + (size_t)(i0 + 4 * ty + c) * 512 + j0 + 4 * tx;
    const float4 d0 = *(const float4*)(ws + OFF_DOT + doff);
    const float4 d1 = *(const float4*)(ws + OFF_DOT + 4 * PLANE + doff);
    const float dA[4] = {d0.x + d1.x, d0.y + d1.y, d0.z + d1.z, d0.w + d1.w};
#pragma unroll
    for (int d = 0; d < 4; ++d) {
      const int p = c * 4 + d;
      const float mu = maA[c] + mbA[d];
      const float msq = (qaA[c] + qbA[d] + 2.f * dA[d]) * (1.f / 512.f);
      const float var = msq - mu * mu;
      const float sv = 1.0f / sqrtf(var + 1e-5f);  // precise (no fast-math)
      Sv[p] = sv;
      Tv[p] = -mu * sv;
      acc[p] = ks ? 0.f : sv * (paA[c] + pbA[d]);  // linear half (ks==0 only)
    }
  }

  int aoff[4], boff[4];
#pragma unroll
  for (int c = 0; c < 4; ++c) {
    const int row = 4 * ty + c;
    aoff[c] = row * 256 + (((row + (row >> 2)) & 15) << 4);
  }
#pragma unroll
  for (int d = 0; d < 4; ++d) {
    const int row = 4 * tx + d;
    boff[d] = row * 256 + (((row + (row >> 2)) & 15) << 4);
  }

  const int kbase = ks << 8;
  for (int kc = 0; kc < 4; ++kc) {
    const int kb = kbase + (kc << 6);
    float4 ag[4], bg[4], pg;
#pragma unroll
    for (int m = 0; m < 4; ++m) {
      ag[m] = *(const float4*)(ws + OFF_A +
               (size_t)(r * 512 + i0 + ty + 16 * m) * 512 + kb + 4 * tx);
      bg[m] = *(const float4*)(ws + OFF_B +
               (size_t)(r * 512 + j0 + ty + 16 * m) * 512 + kb + 4 * tx);
    }
    if (t < 48) {
      const size_t po = (t < 16) ? OFF_P : ((t < 32) ? OFF_Q : OFF_SG);
      pg = *(const float4*)(ws + po + r * 512 + kb + 4 * (t & 15));
    }
    __syncthreads();  // protect previous chunk's LDS reads
#pragma unroll
    for (int m = 0; m < 4; ++m) {
      const int row = ty + 16 * m;
      const int sw = (row + (row >> 2)) & 15;
      *(float4*)((char*)As + row * 256 + ((tx ^ sw) << 4)) = ag[m];
      *(float4*)((char*)Bs + row * 256 + ((tx ^ sw) << 4)) = bg[m];
    }
    if (t < 48) *(float4*)((char*)Pl + t * 16) = pg;
    __syncthreads();

#pragma unroll 4
    for (int k4 = 0; k4 < 16; ++k4) {
      const float4 Pk = *(const float4*)((char*)Pl + (k4 << 4));
      const float4 Qk = *(const float4*)((char*)Pl + 256 + (k4 << 4));
      const float4 Sk = *(const float4*)((char*)Pl + 512 + (k4 << 4));
      float4 av[4], bv[4];
#pragma unroll
      for (int c = 0; c < 4; ++c)
        av[c] = *(const float4*)((char*)As + (aoff[c] ^ (k4 << 4)));
#pragma unroll
      for (int d = 0; d < 4; ++d)
        bv[d] = *(const float4*)((char*)Bs + (boff[d] ^ (k4 << 4)));
#pragma unroll
      for (int kk = 0; kk < 4; ++kk) {
        const float pk = ((const float*)&Pk)[kk];
        const float qk = ((const float*)&Qk)[kk];
        const float sk = ((const float*)&Sk)[kk];
        float aa[4], bb[4];
#pragma unroll
        for (int c = 0; c < 4; ++c) aa[c] = ((const float*)&av[c])[kk];
#pragma unroll
        for (int d = 0; d < 4; ++d) bb[d] = ((const float*)&bv[d])[kk];
#pragma unroll
        for (int c = 0; c < 4; ++c)
#pragma unroll
          for (int d = 0; d < 4; ++d) {
            const int p = c * 4 + d;
            const float u = aa[c] + bb[d];
            const float t1 = fmaf(u, Sv[p], Tv[p]);
            const float h = fmaf(t1, pk, qk);
            acc[p] = fmaf(fabsf(h), sk, acc[p]);  // abs = free VOP3 modifier
          }
      }
    }
  }

  float* dst = ws + OFF_S + (size_t)ks * (4 * PLANE) + (size_t)r * PLANE;
#pragma unroll
  for (int c = 0; c < 4; ++c) {
    float4 v;
    v.x = acc[c * 4 + 0];
    v.y = acc[c * 4 + 1];
    v.z = acc[c * 4 + 2];
    v.w = acc[c * 4 + 3];
    *(float4*)(dst + (size_t)(i0 + 4 * ty + c) * 512 + j0 + 4 * tx) = v;
  }
}

// ---------------- K4: combine + outputs ----------------
__global__ __launch_bounds__(256) void k4_combine(const float* __restrict__ ws,
                                                  const float* __restrict__ img,
                                                  const float* __restrict__ txt,
                                                  const float* __restrict__ b2,
                                                  float* __restrict__ out) {
  const int idx = blockIdx.x * 256 + threadIdx.x;
  const int i = idx >> 9, j = idx & 511;
  const float* s0 = ws + OFF_S;
  const float* s1 = ws + OFF_S + 4 * PLANE;
  const float* qsp = ws + OFF_QSP;
  float best = -3.4e38f;
  int rel = 0;
#pragma unroll
  for (int r = 0; r < 4; ++r) {
    const float cr = b2[r] + qsp[2 * r] + qsp[2 * r + 1];
    const float s = s0[r * PLANE + idx] + s1[r * PLANE + idx] + cr;
    if (s > best) { best = s; rel = r; }  // strict > == first-index argmax
  }
  out[idx] = (i < 256) ? img[idx] : txt[idx - 131072];
  out[PLANE + idx] = best;
  out[2 * PLANE + idx] = (float)rel;
  out[3 * PLANE + idx] = (i != j && (double)best > 0.2) ? 1.0f : 0.0f;
}

extern "C" void kernel_launch(void* const* d_in, const int* in_sizes, int n_in,
                              void* d_out, int out_size, void* d_ws, size_t ws_size,
                              hipStream_t stream) {
  const float* img   = (const float*)d_in[0];
  const float* txt   = (const float*)d_in[1];
  const float* W1    = (const float*)d_in[2];
  const float* b1    = (const float*)d_in[3];
  const float* gamma = (const float*)d_in[4];
  const float* beta  = (const float*)d_in[5];
  const float* w2    = (const float*)d_in[6];
  const float* b2    = (const float*)d_in[7];
  float* ws  = (float*)d_ws;
  float* out = (float*)d_out;
  (void)in_sizes; (void)n_in; (void)out_size; (void)ws_size;

  hipLaunchKernelGGL(k0_gemm,    dim3(512),  dim3(256), 0, stream, img, txt, W1, b1, ws);
  hipLaunchKernelGGL(k1_stats,   dim3(1024), dim3(256), 0, stream, ws, gamma, beta, w2);
  hipLaunchKernelGGL(k2_dot,     dim3(512),  dim3(256), 0, stream, ws);
  hipLaunchKernelGGL(k3_score,   dim3(512),  dim3(256), 0, stream, ws);
  hipLaunchKernelGGL(k4_combine, dim3(1024), dim3(256), 0, stream, ws, img, txt, b2, out);
}

// Round 3
// 202.648 us; speedup vs baseline: 1.0222x; 1.0222x over previous
//
#include <hip/hip_runtime.h>
#include <math.h>

// DynamicRelationModeler: x=concat(img,txt) [512x512]; per r: a=x@Wl_r^T, b=x@Wr_r^T;
// h=a_i+b_j+b1_r; LN over H; s=relu(hn)@w2_r+b2_r; argmax/max over r; mask.
//
// Score decomposition (exact): relu(z) = (z+|z|)/2, so with P=0.5*w2*gamma, Q=0.5*w2*beta:
//   s = sv*(PA'_i + PB'_j) + QS_r + sum_k sign(w2_k)*|t_k*P_k + Q_k| + b2_r
// where t_k = (a_ik + b_jk - mu)*sv, PA'_i = sum_k P_k*(a_ik - ma_i)  (per-row precompute).
// Inner loop = 4 VALU ops per (pair,k): add, fma, fma, fma-with-abs-modifier.
//
// ws layout (floats):
//   Aarr [4][512][512], Barr [4][512][512] (b1 folded), dotp [2][4][512][512],
//   Spart[2][4][512][512], then small arrays (row stats, planes) at 24*PLANE.

namespace {
constexpr size_t PLANE  = 512 * 512;            // 262144
constexpr size_t OFF_A   = 0;
constexpr size_t OFF_B   = OFF_A + 4 * PLANE;
constexpr size_t OFF_DOT = OFF_B + 4 * PLANE;
constexpr size_t OFF_S   = OFF_DOT + 8 * PLANE;
constexpr size_t OFF_MA  = OFF_S + 8 * PLANE;   // 24*PLANE
constexpr size_t OFF_QA  = OFF_MA + 2048;
constexpr size_t OFF_PAp = OFF_QA + 2048;
constexpr size_t OFF_MB  = OFF_PAp + 2048;
constexpr size_t OFF_QB  = OFF_MB + 2048;
constexpr size_t OFF_PBp = OFF_QB + 2048;
constexpr size_t OFF_P   = OFF_PBp + 2048;
constexpr size_t OFF_Q   = OFF_P + 2048;
constexpr size_t OFF_SG  = OFF_Q + 2048;
constexpr size_t OFF_QSP = OFF_SG + 2048;       // 8 floats
}

// ---------------- K0: input GEMM  C[n][4096] = x @ [Wl|Wr]^T ----------------
__global__ __launch_bounds__(256) void k0_gemm(const float* __restrict__ img,
                                               const float* __restrict__ txt,
                                               const float* __restrict__ W1,
                                               const float* __restrict__ b1,
                                               float* __restrict__ ws) {
  const int b = blockIdx.x;
  const int it = b >> 6;
  const int ct = b & 63;
  const int which = ct >> 5;
  const int r = (ct >> 3) & 3;
  const int ht = ct & 7;
  const int i0 = it << 6, h0 = ht << 6;
  const int t = threadIdx.x;
  const int tx = t & 15, ty = t >> 4;

  __shared__ float Xs[16 * 68];
  __shared__ float Wsm[16 * 68];

  float acc[16], pacc[16];
#pragma unroll
  for (int p = 0; p < 16; ++p) { acc[p] = 0.f; pacc[p] = 0.f; }

  const int srow = t >> 2;
  const int sf4 = (t & 3) << 2;
  const int xi = i0 + srow;
  const float* xrow = (xi < 256) ? (img + (size_t)xi * 512)
                                 : (txt + (size_t)(xi - 256) * 512);
  const float* wrow = W1 + (size_t)(r * 512 + h0 + srow) * 1024 + which * 512;

  for (int k0 = 0; k0 < 512; k0 += 16) {
    const float4 xv = *(const float4*)(xrow + k0 + sf4);
    const float4 wv = *(const float4*)(wrow + k0 + sf4);
    __syncthreads();
    Xs[(sf4 + 0) * 68 + srow] = xv.x;
    Xs[(sf4 + 1) * 68 + srow] = xv.y;
    Xs[(sf4 + 2) * 68 + srow] = xv.z;
    Xs[(sf4 + 3) * 68 + srow] = xv.w;
    Wsm[(sf4 + 0) * 68 + srow] = wv.x;
    Wsm[(sf4 + 1) * 68 + srow] = wv.y;
    Wsm[(sf4 + 2) * 68 + srow] = wv.z;
    Wsm[(sf4 + 3) * 68 + srow] = wv.w;
    __syncthreads();
#pragma unroll
    for (int k = 0; k < 16; ++k) {
      const float4 a4 = *(const float4*)&Xs[k * 68 + 4 * ty];
      const float4 b4 = *(const float4*)&Wsm[k * 68 + 4 * tx];
      const float av[4] = {a4.x, a4.y, a4.z, a4.w};
      const float bv[4] = {b4.x, b4.y, b4.z, b4.w};
#pragma unroll
      for (int c = 0; c < 4; ++c)
#pragma unroll
        for (int d = 0; d < 4; ++d)
          pacc[c * 4 + d] = fmaf(av[c], bv[d], pacc[c * 4 + d]);
    }
#pragma unroll
    for (int p = 0; p < 16; ++p) { acc[p] += pacc[p]; pacc[p] = 0.f; }
  }

  float4 bb = make_float4(0.f, 0.f, 0.f, 0.f);
  if (which) bb = *(const float4*)(b1 + r * 512 + h0 + 4 * tx);
  float* dst = ws + (which ? OFF_B : OFF_A) + (size_t)r * PLANE;
#pragma unroll
  for (int c = 0; c < 4; ++c) {
    float4 v;
    v.x = acc[c * 4 + 0] + bb.x;
    v.y = acc[c * 4 + 1] + bb.y;
    v.z = acc[c * 4 + 2] + bb.z;
    v.w = acc[c * 4 + 3] + bb.w;
    *(float4*)(dst + (size_t)(i0 + 4 * ty + c) * 512 + h0 + 4 * tx) = v;
  }
}

// ---------------- K1: row stats + weighted row sums + planes ----------------
__global__ __launch_bounds__(256) void k1_stats(float* __restrict__ ws,
                                                const float* __restrict__ gamma,
                                                const float* __restrict__ beta,
                                                const float* __restrict__ w2) {
  __shared__ float red[4];
  const int t = threadIdx.x;
  const int gw = (blockIdx.x * 256 + t) >> 6;
  const int lane = t & 63;
  const int which = gw >> 11;
  const int rr = (gw >> 9) & 3;
  const int row = gw & 511;
  const float* src =
      ws + (which ? OFF_B : OFF_A) + (size_t)(rr * 512 + row) * 512 + lane * 8;
  const float* gp = gamma + rr * 512 + lane * 8;
  const float* wp = w2 + rr * 512 + lane * 8;
  float s = 0.f, q = 0.f, pa = 0.f, gg = 0.f;
#pragma unroll
  for (int c = 0; c < 2; ++c) {
    const float4 v = *(const float4*)(src + c * 4);
    const float4 g = *(const float4*)(gp + c * 4);
    const float4 w = *(const float4*)(wp + c * 4);
    const float vv[4] = {v.x, v.y, v.z, v.w};
    const float gv[4] = {g.x, g.y, g.z, g.w};
    const float wv[4] = {w.x, w.y, w.z, w.w};
#pragma unroll
    for (int e = 0; e < 4; ++e) {
      const float p = 0.5f * gv[e] * wv[e];
      s += vv[e];
      q += vv[e] * vv[e];
      pa += p * vv[e];
      gg += p;
    }
  }
#pragma unroll
  for (int off = 32; off >= 1; off >>= 1) {
    s += __shfl_down(s, off, 64);
    q += __shfl_down(q, off, 64);
    pa += __shfl_down(pa, off, 64);
    gg += __shfl_down(gg, off, 64);
  }
  if (lane == 0) {
    const float ma = s * (1.f / 512.f);
    ws[(which ? OFF_MB : OFF_MA) + rr * 512 + row] = ma;
    ws[(which ? OFF_QB : OFF_QA) + rr * 512 + row] = q;
    ws[(which ? OFF_PBp : OFF_PAp) + rr * 512 + row] = pa - ma * gg;
  }
  if (blockIdx.x < 8) {
    const int idx = blockIdx.x * 256 + t;  // r*512+k
    const float g = gamma[idx], be = beta[idx], w = w2[idx];
    const float qv = 0.5f * be * w;
    ws[OFF_P + idx] = 0.5f * g * w;
    ws[OFF_Q + idx] = qv;
    ws[OFF_SG + idx] = copysignf(1.f, w);
    float qs = qv;
#pragma unroll
    for (int off = 32; off >= 1; off >>= 1) qs += __shfl_down(qs, off, 64);
    if (lane == 0) red[t >> 6] = qs;
    __syncthreads();
    if (t == 0) ws[OFF_QSP + blockIdx.x] = red[0] + red[1] + red[2] + red[3];
  }
}

// ---------------- K2: pairwise dot  dotp[ks][r][i][j] = sum_k a.b' ----------------
__global__ __launch_bounds__(256) void k2_dot(float* __restrict__ ws) {
  const int b = blockIdx.x;
  const int jt = b & 7, it = (b >> 3) & 7, r = (b >> 6) & 3, ks = b >> 8;
  const int i0 = it << 6, j0 = jt << 6;
  const int kb = ks << 8;
  const int t = threadIdx.x;
  const int tx = t & 15, ty = t >> 4;

  __shared__ float As[16 * 68];
  __shared__ float Bs[16 * 68];

  float acc[16];
#pragma unroll
  for (int p = 0; p < 16; ++p) acc[p] = 0.f;

  const int srow = t >> 2, sf4 = (t & 3) << 2;
  const float* arow = ws + OFF_A + (size_t)(r * 512 + i0 + srow) * 512 + kb;
  const float* brow = ws + OFF_B + (size_t)(r * 512 + j0 + srow) * 512 + kb;

  for (int k0 = 0; k0 < 256; k0 += 16) {
    const float4 av = *(const float4*)(arow + k0 + sf4);
    const float4 bv = *(const float4*)(brow + k0 + sf4);
    __syncthreads();
    As[(sf4 + 0) * 68 + srow] = av.x;
    As[(sf4 + 1) * 68 + srow] = av.y;
    As[(sf4 + 2) * 68 + srow] = av.z;
    As[(sf4 + 3) * 68 + srow] = av.w;
    Bs[(sf4 + 0) * 68 + srow] = bv.x;
    Bs[(sf4 + 1) * 68 + srow] = bv.y;
    Bs[(sf4 + 2) * 68 + srow] = bv.z;
    Bs[(sf4 + 3) * 68 + srow] = bv.w;
    __syncthreads();
#pragma unroll
    for (int k = 0; k < 16; ++k) {
      const float4 a4 = *(const float4*)&As[k * 68 + 4 * ty];
      const float4 b4 = *(const float4*)&Bs[k * 68 + 4 * tx];
      const float av2[4] = {a4.x, a4.y, a4.z, a4.w};
      const float bv2[4] = {b4.x, b4.y, b4.z, b4.w};
#pragma unroll
      for (int c = 0; c < 4; ++c)
#pragma unroll
        for (int d = 0; d < 4; ++d)
          acc[c * 4 + d] = fmaf(av2[c], bv2[d], acc[c * 4 + d]);
    }
  }
  float* dst = ws + OFF_DOT + (size_t)ks * (4 * PLANE) + (size_t)r * PLANE;
#pragma unroll
  for (int c = 0; c < 4; ++c) {
    float4 v;
    v.x = acc[c * 4 + 0]; v.y = acc[c * 4 + 1];
    v.z = acc[c * 4 + 2]; v.w = acc[c * 4 + 3];
    *(float4*)(dst + (size_t)(i0 + 4 * ty + c) * 512 + j0 + 4 * tx) = v;
  }
}

// ---------------- K3: score kernel (4-op inner loop) ----------------
// grid 1024 = 16jt(32) x 8it(64) x 4r x 2ks; block 256 (16tx x 16ty; 4i x 2j reg tile)
// -> 4 blocks/CU, 16 waves/CU. LDS XOR-swizzled 16B chunks: chunk = k4 ^ ((row+(row>>2))&15)
__global__ __launch_bounds__(256) void k3_score(float* __restrict__ ws) {
  const int b = blockIdx.x;
  const int jt = b & 15, it = (b >> 4) & 7, r = (b >> 7) & 3, ks = b >> 9;
  const int i0 = it << 6, j0 = jt << 5;
  const int t = threadIdx.x;
  const int tx = t & 15, ty = t >> 4;

  __shared__ float As[64 * 64];   // 16 KB
  __shared__ float Bs[32 * 64];   //  8 KB
  __shared__ float Pl[3 * 64];    // P | Q | sign planes for current 64-k chunk

  const float4 mav = *(const float4*)(ws + OFF_MA + r * 512 + i0 + 4 * ty);
  const float4 qav = *(const float4*)(ws + OFF_QA + r * 512 + i0 + 4 * ty);
  const float4 pav = *(const float4*)(ws + OFF_PAp + r * 512 + i0 + 4 * ty);
  const float2 mbv = *(const float2*)(ws + OFF_MB + r * 512 + j0 + 2 * tx);
  const float2 qbv = *(const float2*)(ws + OFF_QB + r * 512 + j0 + 2 * tx);
  const float2 pbv = *(const float2*)(ws + OFF_PBp + r * 512 + j0 + 2 * tx);
  const float maA[4] = {mav.x, mav.y, mav.z, mav.w};
  const float qaA[4] = {qav.x, qav.y, qav.z, qav.w};
  const float paA[4] = {pav.x, pav.y, pav.z, pav.w};
  const float mbA[2] = {mbv.x, mbv.y};
  const float qbA[2] = {qbv.x, qbv.y};
  const float pbA[2] = {pbv.x, pbv.y};

  float Sv[8], Tv[8], acc[8];
#pragma unroll
  for (int c = 0; c < 4; ++c) {
    const size_t doff =
        (size_t)r * PLANE + (size_t)(i0 + 4 * ty + c) * 512 + j0 + 2 * tx;
    const float2 d0 = *(const float2*)(ws + OFF_DOT + doff);
    const float2 d1 = *(const float2*)(ws + OFF_DOT + 4 * PLANE + doff);
    const float dA[2] = {d0.x + d1.x, d0.y + d1.y};
#pragma unroll
    for (int d = 0; d < 2; ++d) {
      const int p = c * 2 + d;
      const float mu = maA[c] + mbA[d];
      const float msq = (qaA[c] + qbA[d] + 2.f * dA[d]) * (1.f / 512.f);
      const float var = msq - mu * mu;
      const float sv = 1.0f / sqrtf(var + 1e-5f);  // precise (no fast-math)
      Sv[p] = sv;
      Tv[p] = -mu * sv;
      acc[p] = ks ? 0.f : sv * (paA[c] + pbA[d]);  // linear half (ks==0 only)
    }
  }

  int aoff[4], boff[2];
#pragma unroll
  for (int c = 0; c < 4; ++c) {
    const int row = 4 * ty + c;
    aoff[c] = row * 256 + (((row + (row >> 2)) & 15) << 4);
  }
#pragma unroll
  for (int d = 0; d < 2; ++d) {
    const int row = 2 * tx + d;
    boff[d] = row * 256 + (((row + (row >> 2)) & 15) << 4);
  }

  // staging index precompute
  const int arow_s = t >> 2;             // 0..63
  const int acol_s = t & 3;              // f4 col base, +4m
  const int swA = (arow_s + (arow_s >> 2)) & 15;
  const int brow_s = t >> 3;             // 0..31
  const int bcol_s = t & 7;              // f4 col base, +8m
  const int swB = (brow_s + (brow_s >> 2)) & 15;
  const float* agbase =
      ws + OFF_A + (size_t)(r * 512 + i0 + arow_s) * 512;
  const float* bgbase =
      ws + OFF_B + (size_t)(r * 512 + j0 + brow_s) * 512;

  const int kbase = ks << 8;
  for (int kc = 0; kc < 4; ++kc) {
    const int kb = kbase + (kc << 6);
    float4 ag[4], bg[2], pg;
#pragma unroll
    for (int m = 0; m < 4; ++m)
      ag[m] = *(const float4*)(agbase + kb + 4 * (acol_s + 4 * m));
#pragma unroll
    for (int m = 0; m < 2; ++m)
      bg[m] = *(const float4*)(bgbase + kb + 4 * (bcol_s + 8 * m));
    if (t < 48) {
      const size_t po = (t < 16) ? OFF_P : ((t < 32) ? OFF_Q : OFF_SG);
      pg = *(const float4*)(ws + po + r * 512 + kb + 4 * (t & 15));
    }
    __syncthreads();  // protect previous chunk's LDS reads
#pragma unroll
    for (int m = 0; m < 4; ++m)
      *(float4*)((char*)As + arow_s * 256 + (((acol_s + 4 * m) ^ swA) << 4)) = ag[m];
#pragma unroll
    for (int m = 0; m < 2; ++m)
      *(float4*)((char*)Bs + brow_s * 256 + (((bcol_s + 8 * m) ^ swB) << 4)) = bg[m];
    if (t < 48) *(float4*)((char*)Pl + t * 16) = pg;
    __syncthreads();

#pragma unroll 4
    for (int k4 = 0; k4 < 16; ++k4) {
      const float4 Pk = *(const float4*)((char*)Pl + (k4 << 4));
      const float4 Qk = *(const float4*)((char*)Pl + 256 + (k4 << 4));
      const float4 Sk = *(const float4*)((char*)Pl + 512 + (k4 << 4));
      float4 av[4], bv[2];
#pragma unroll
      for (int c = 0; c < 4; ++c)
        av[c] = *(const float4*)((char*)As + (aoff[c] ^ (k4 << 4)));
#pragma unroll
      for (int d = 0; d < 2; ++d)
        bv[d] = *(const float4*)((char*)Bs + (boff[d] ^ (k4 << 4)));
#pragma unroll
      for (int kk = 0; kk < 4; ++kk) {
        const float pk = ((const float*)&Pk)[kk];
        const float qk = ((const float*)&Qk)[kk];
        const float sk = ((const float*)&Sk)[kk];
        float aa[4], bb[2];
#pragma unroll
        for (int c = 0; c < 4; ++c) aa[c] = ((const float*)&av[c])[kk];
#pragma unroll
        for (int d = 0; d < 2; ++d) bb[d] = ((const float*)&bv[d])[kk];
#pragma unroll
        for (int c = 0; c < 4; ++c)
#pragma unroll
          for (int d = 0; d < 2; ++d) {
            const int p = c * 2 + d;
            const float u = aa[c] + bb[d];
            const float t1 = fmaf(u, Sv[p], Tv[p]);
            const float h = fmaf(t1, pk, qk);
            acc[p] = fmaf(fabsf(h), sk, acc[p]);  // abs = free VOP3 modifier
          }
      }
    }
  }

  float* dst = ws + OFF_S + (size_t)ks * (4 * PLANE) + (size_t)r * PLANE;
#pragma unroll
  for (int c = 0; c < 4; ++c) {
    float2 v;
    v.x = acc[c * 2 + 0];
    v.y = acc[c * 2 + 1];
    *(float2*)(dst + (size_t)(i0 + 4 * ty + c) * 512 + j0 + 2 * tx) = v;
  }
}

// ---------------- K4: combine + outputs ----------------
__global__ __launch_bounds__(256) void k4_combine(const float* __restrict__ ws,
                                                  const float* __restrict__ img,
                                                  const float* __restrict__ txt,
                                                  const float* __restrict__ b2,
                                                  float* __restrict__ out) {
  const int idx = blockIdx.x * 256 + threadIdx.x;
  const int i = idx >> 9, j = idx & 511;
  const float* s0 = ws + OFF_S;
  const float* s1 = ws + OFF_S + 4 * PLANE;
  const float* qsp = ws + OFF_QSP;
  float best = -3.4e38f;
  int rel = 0;
#pragma unroll
  for (int r = 0; r < 4; ++r) {
    const float cr = b2[r] + qsp[2 * r] + qsp[2 * r + 1];
    const float s = s0[r * PLANE + idx] + s1[r * PLANE + idx] + cr;
    if (s > best) { best = s; rel = r; }  // strict > == first-index argmax
  }
  out[idx] = (i < 256) ? img[idx] : txt[idx - 131072];
  out[PLANE + idx] = best;
  out[2 * PLANE + idx] = (float)rel;
  out[3 * PLANE + idx] = (i != j && (double)best > 0.2) ? 1.0f : 0.0f;
}

extern "C" void kernel_launch(void* const* d_in, const int* in_sizes, int n_in,
                              void* d_out, int out_size, void* d_ws, size_t ws_size,
                              hipStream_t stream) {
  const float* img   = (const float*)d_in[0];
  const float* txt   = (const float*)d_in[1];
  const float* W1    = (const float*)d_in[2];
  const float* b1    = (const float*)d_in[3];
  const float* gamma = (const float*)d_in[4];
  const float* beta  = (const float*)d_in[5];
  const float* w2    = (const float*)d_in[6];
  const float* b2    = (const float*)d_in[7];
  float* ws  = (float*)d_ws;
  float* out = (float*)d_out;
  (void)in_sizes; (void)n_in; (void)out_size; (void)ws_size;

  hipLaunchKernelGGL(k0_gemm,    dim3(512),  dim3(256), 0, stream, img, txt, W1, b1, ws);
  hipLaunchKernelGGL(k1_stats,   dim3(1024), dim3(256), 0, stream, ws, gamma, beta, w2);
  hipLaunchKernelGGL(k2_dot,     dim3(512),  dim3(256), 0, stream, ws);
  hipLaunchKernelGGL(k3_score,   dim3(1024), dim3(256), 0, stream, ws);
  hipLaunchKernelGGL(k4_combine, dim3(1024), dim3(256), 0, stream, ws, img, txt, b2, out);
}